// Round 1
// baseline (531.594 us; speedup 1.0000x reference)
//
#include <hip/hip_runtime.h>
#include <hip/hip_bf16.h>

// ---------------------------------------------------------------------------
// SpatialInteraction: per-batch channel self-attention
//   S = X X^T  (c=1024, n=4096), attn = softmax_rows(S), out = attn X
// Pipeline: cvt+transpose -> bt-GEMM (S) -> row softmax -> bt-GEMM (out)
// bf16 MFMA (16x16x32), m97-style 128x128 tile, global_load_lds staging.
// ---------------------------------------------------------------------------

typedef float  f32x4  __attribute__((ext_vector_type(4)));
typedef __bf16 bf16x8 __attribute__((ext_vector_type(8)));

#define BATCH 16
#define C_DIM 1024
#define N_DIM 4096

__device__ __forceinline__ unsigned short f2bf(float f) {
  unsigned u = __float_as_uint(f);
  u += 0x7fffu + ((u >> 16) & 1u);        // round-to-nearest-even
  return (unsigned short)(u >> 16);
}

__device__ __forceinline__ void gld_lds16(const void* g, void* l) {
  __builtin_amdgcn_global_load_lds(
      (const __attribute__((address_space(1))) unsigned int*)g,
      (__attribute__((address_space(3))) unsigned int*)l, 16, 0, 0);
}

// ---------------------------------------------------------------------------
// Kernel 0: fp32 -> bf16 copy (xb[c][n]) + transposed copy (xbT[n][c]).
// 64x64 tile per block, 256 threads, float4 loads / ushort4 stores.
// ---------------------------------------------------------------------------
__global__ __launch_bounds__(256) void cvt_xpose(const float* __restrict__ x,
                                                 unsigned short* __restrict__ xb,
                                                 unsigned short* __restrict__ xbT) {
  __shared__ unsigned short tile[64][68];   // +4 pad keeps ushort4 alignment
  const int b  = blockIdx.z;
  const int c0 = blockIdx.y * 64;
  const int n0 = blockIdx.x * 64;
  const int t  = threadIdx.x;

  const float* xp = x + ((size_t)b * C_DIM + c0) * N_DIM + n0;
  const int tn = (t & 15) * 4;   // n offset within tile
  const int tc = t >> 4;         // 0..15

#pragma unroll
  for (int i = 0; i < 4; ++i) {
    const int c = i * 16 + tc;
    const float4 v = *(const float4*)(xp + (size_t)c * N_DIM + tn);
    ushort4 u;
    u.x = f2bf(v.x); u.y = f2bf(v.y); u.z = f2bf(v.z); u.w = f2bf(v.w);
    *(ushort4*)&tile[c][tn] = u;
    *(ushort4*)(xb + ((size_t)b * C_DIM + c0 + c) * N_DIM + n0 + tn) = u;
  }
  __syncthreads();

  const int pc = (t & 15) * 4;   // c offset within tile
  const int pn = t >> 4;
#pragma unroll
  for (int i = 0; i < 4; ++i) {
    const int n = i * 16 + pn;
    ushort4 u;
    u.x = tile[pc + 0][n];
    u.y = tile[pc + 1][n];
    u.z = tile[pc + 2][n];
    u.w = tile[pc + 3][n];
    *(ushort4*)(xbT + ((size_t)b * N_DIM + n0 + n) * C_DIM + c0 + pc) = u;
  }
}

// ---------------------------------------------------------------------------
// Kernel 1/3: C[M][N] = A[M][K] * B[N][K]^T, A/B bf16 row-major, C fp32.
// 128x128 tile, BK=64, 256 threads = 4 waves (2x2), each wave 64x64 = 4x4
// fragments of mfma_f32_16x16x32_bf16. global_load_lds width-16 staging,
// 2 barriers per K-step (m97 structure).
// grid: (N/128, M/128, batch)
// ---------------------------------------------------------------------------
__global__ __launch_bounds__(256, 3)
void gemm_bt(const unsigned short* __restrict__ A,
             const unsigned short* __restrict__ B,
             float* __restrict__ C,
             int K, int lda, int ldb, int ldc,
             long sA, long sB, long sC) {
  __shared__ unsigned short As[128 * 64];
  __shared__ unsigned short Bs[128 * 64];

  const int tid  = threadIdx.x;
  const int lane = tid & 63;
  const int wid  = tid >> 6;
  const int wrow = wid >> 1;        // 0..1
  const int wcol = wid & 1;         // 0..1
  const int r    = lane & 15;
  const int kg   = lane >> 4;       // 0..3

  const unsigned short* Ab = A + (size_t)blockIdx.z * sA + (size_t)blockIdx.y * 128 * lda;
  const unsigned short* Bb = B + (size_t)blockIdx.z * sB + (size_t)blockIdx.x * 128 * ldb;

  f32x4 acc[4][4] = {};

  for (int k0 = 0; k0 < K; k0 += 64) {
    // ---- stage A tile (128 rows x 64 cols) : 1024 x 16B chunks ----
#pragma unroll
    for (int it = 0; it < 4; ++it) {
      const int chunk = it * 256 + tid;
      const int row = chunk >> 3, c16 = chunk & 7;
      gld_lds16(Ab + (size_t)row * lda + k0 + c16 * 8, &As[chunk * 8]);
    }
    // ---- stage B tile ----
#pragma unroll
    for (int it = 0; it < 4; ++it) {
      const int chunk = it * 256 + tid;
      const int row = chunk >> 3, c16 = chunk & 7;
      gld_lds16(Bb + (size_t)row * ldb + k0 + c16 * 8, &Bs[chunk * 8]);
    }
    __syncthreads();   // drains vmcnt(0): tiles resident

#pragma unroll
    for (int kk = 0; kk < 2; ++kk) {
      bf16x8 af[4], bfr[4];
#pragma unroll
      for (int m = 0; m < 4; ++m)
        af[m] = *(const bf16x8*)&As[(wrow * 64 + m * 16 + r) * 64 + kk * 32 + kg * 8];
#pragma unroll
      for (int n = 0; n < 4; ++n)
        bfr[n] = *(const bf16x8*)&Bs[(wcol * 64 + n * 16 + r) * 64 + kk * 32 + kg * 8];
#pragma unroll
      for (int m = 0; m < 4; ++m)
#pragma unroll
        for (int n = 0; n < 4; ++n)
          acc[m][n] = __builtin_amdgcn_mfma_f32_16x16x32_bf16(af[m], bfr[n], acc[m][n], 0, 0, 0);
    }
    __syncthreads();   // protect LDS before next stage
  }

  // ---- epilogue: C/D layout col = lane&15, row = (lane>>4)*4 + j ----
  float* Cb = C + (size_t)blockIdx.z * sC;
#pragma unroll
  for (int m = 0; m < 4; ++m) {
#pragma unroll
    for (int n = 0; n < 4; ++n) {
      const int row = blockIdx.y * 128 + wrow * 64 + m * 16 + kg * 4;
      const int col = blockIdx.x * 128 + wcol * 64 + n * 16 + r;
      const f32x4 a = acc[m][n];
#pragma unroll
      for (int j = 0; j < 4; ++j)
        Cb[(size_t)(row + j) * ldc + col] = a[j];
    }
  }
}

// ---------------------------------------------------------------------------
// Kernel 2: row softmax, S (fp32, 16384 rows x 1024) -> attn (bf16).
// One 256-thread block per row; float4 per thread.
// ---------------------------------------------------------------------------
__global__ __launch_bounds__(256) void softmax_rows(const float* __restrict__ S,
                                                    unsigned short* __restrict__ P) {
  __shared__ float redm[4];
  __shared__ float reds[4];
  const int t = threadIdx.x;
  const int wid = t >> 6, lane = t & 63;
  const size_t row = blockIdx.x;

  const float4 v = ((const float4*)(S + row * 1024))[t];

  float m = fmaxf(fmaxf(v.x, v.y), fmaxf(v.z, v.w));
#pragma unroll
  for (int o = 32; o >= 1; o >>= 1) m = fmaxf(m, __shfl_xor(m, o));
  if (lane == 0) redm[wid] = m;
  __syncthreads();
  m = fmaxf(fmaxf(redm[0], redm[1]), fmaxf(redm[2], redm[3]));

  const float e0 = expf(v.x - m), e1 = expf(v.y - m);
  const float e2 = expf(v.z - m), e3 = expf(v.w - m);
  float s = (e0 + e1) + (e2 + e3);
#pragma unroll
  for (int o = 32; o >= 1; o >>= 1) s += __shfl_xor(s, o);
  if (lane == 0) reds[wid] = s;
  __syncthreads();
  s = (reds[0] + reds[1]) + (reds[2] + reds[3]);

  const float inv = 1.0f / s;
  ushort4 u;
  u.x = f2bf(e0 * inv); u.y = f2bf(e1 * inv);
  u.z = f2bf(e2 * inv); u.w = f2bf(e3 * inv);
  ((ushort4*)(P + row * 1024))[t] = u;
}

// ---------------------------------------------------------------------------
extern "C" void kernel_launch(void* const* d_in, const int* in_sizes, int n_in,
                              void* d_out, int out_size, void* d_ws, size_t ws_size,
                              hipStream_t stream) {
  const float* x = (const float*)d_in[0];
  float* out = (float*)d_out;

  // workspace: xb (128 MiB) | xbT (128 MiB); attn overlays xb (dead after GEMM1)
  unsigned short* xb   = (unsigned short*)d_ws;
  unsigned short* xbT  = xb + (size_t)BATCH * C_DIM * N_DIM;
  unsigned short* attn = xb;
  // scores staged in d_out's first 64 MiB (overwritten by final GEMM)
  float* S = out;

  cvt_xpose<<<dim3(N_DIM / 64, C_DIM / 64, BATCH), 256, 0, stream>>>(x, xb, xbT);

  // S[c][d] = sum_n xb[c][n] xb[d][n]   (M=N=1024, K=4096)
  gemm_bt<<<dim3(C_DIM / 128, C_DIM / 128, BATCH), 256, 0, stream>>>(
      xb, xb, S, N_DIM, N_DIM, N_DIM, C_DIM,
      (long)C_DIM * N_DIM, (long)C_DIM * N_DIM, (long)C_DIM * C_DIM);

  softmax_rows<<<dim3(BATCH * C_DIM), 256, 0, stream>>>(S, attn);

  // out[c][n] = sum_d attn[c][d] xbT[n][d]  (M=1024, N=4096, K=1024)
  gemm_bt<<<dim3(N_DIM / 128, C_DIM / 128, BATCH), 256, 0, stream>>>(
      attn, xbT, out, C_DIM, C_DIM, C_DIM, N_DIM,
      (long)C_DIM * C_DIM, (long)N_DIM * C_DIM, (long)C_DIM * N_DIM);
}

// Round 3
// 383.576 us; speedup vs baseline: 1.3859x; 1.3859x over previous
//
#include <hip/hip_runtime.h>
#include <hip/hip_bf16.h>

// ---------------------------------------------------------------------------
// SpatialInteraction: per-batch channel self-attention
//   S = X X^T  (c=1024, n=4096), attn = softmax_rows(S), out = attn X
// Pipeline: cvt+transpose -> 256^2 deep-pipelined bt-GEMM (S) -> softmax ->
//           256^2 bt-GEMM (out).
// GEMM: 256x256 tile, BK=64, 512 thr / 8 waves, T2 chunk-XOR swizzle,
// 4-phase counted-vmcnt pipeline (T3+T4), setprio around MFMA (T5).
// R3 fix: main-loop stage_half calls passed the LDS dest as the global
// source (aperture fault -> SIGABRT). Sources are now Ab/Bb.
// ---------------------------------------------------------------------------

typedef float  f32x4  __attribute__((ext_vector_type(4)));
typedef __bf16 bf16x8 __attribute__((ext_vector_type(8)));

#define BATCH 16
#define C_DIM 1024
#define N_DIM 4096

#define WAITVM(N) asm volatile("s_waitcnt vmcnt(" #N ")" ::: "memory")

__device__ __forceinline__ void fence_() { asm volatile("" ::: "memory"); }
__device__ __forceinline__ void bar_() { fence_(); __builtin_amdgcn_s_barrier(); fence_(); }

__device__ __forceinline__ unsigned short f2bf(float f) {
  unsigned u = __float_as_uint(f);
  u += 0x7fffu + ((u >> 16) & 1u);        // round-to-nearest-even
  return (unsigned short)(u >> 16);
}

__device__ __forceinline__ void gld_lds16(const void* g, void* l) {
  __builtin_amdgcn_global_load_lds(
      (const __attribute__((address_space(1))) unsigned int*)g,
      (__attribute__((address_space(3))) unsigned int*)l, 16, 0, 0);
}

// ---------------------------------------------------------------------------
// Kernel 0: fp32 -> bf16 copy (xb[c][n]) + transposed copy (xbT[n][c]).
// ---------------------------------------------------------------------------
__global__ __launch_bounds__(256) void cvt_xpose(const float* __restrict__ x,
                                                 unsigned short* __restrict__ xb,
                                                 unsigned short* __restrict__ xbT) {
  __shared__ unsigned short tile[64][68];
  const int b  = blockIdx.z;
  const int c0 = blockIdx.y * 64;
  const int n0 = blockIdx.x * 64;
  const int t  = threadIdx.x;

  const float* xp = x + ((size_t)b * C_DIM + c0) * N_DIM + n0;
  const int tn = (t & 15) * 4;
  const int tc = t >> 4;

#pragma unroll
  for (int i = 0; i < 4; ++i) {
    const int c = i * 16 + tc;
    const float4 v = *(const float4*)(xp + (size_t)c * N_DIM + tn);
    ushort4 u;
    u.x = f2bf(v.x); u.y = f2bf(v.y); u.z = f2bf(v.z); u.w = f2bf(v.w);
    *(ushort4*)&tile[c][tn] = u;
    *(ushort4*)(xb + ((size_t)b * C_DIM + c0 + c) * N_DIM + n0 + tn) = u;
  }
  __syncthreads();

  const int pc = (t & 15) * 4;
  const int pn = t >> 4;
#pragma unroll
  for (int i = 0; i < 4; ++i) {
    const int n = i * 16 + pn;
    ushort4 u;
    u.x = tile[pc + 0][n];
    u.y = tile[pc + 1][n];
    u.z = tile[pc + 2][n];
    u.w = tile[pc + 3][n];
    *(ushort4*)(xbT + ((size_t)b * N_DIM + n0 + n) * C_DIM + c0 + pc) = u;
  }
}

// ---------------------------------------------------------------------------
// 256^2 bt-GEMM helpers
// LDS element layout (per matrix, per buffer): row in 0..255, 64 bf16/row,
// 8 x 16B chunks/row; swizzle: chunk' = chunk ^ (row & 7). LDS itself is
// linear; the XOR is applied to the GLOBAL source on stage and to the
// ds_read address on read (both-sides involution, m201 pattern).
// ---------------------------------------------------------------------------

// Stage half H (128 rows) of one matrix tile into matbase (+H*8192 elems).
// 2 x global_load_lds(16B) per thread; 2 VMEM instrs per wave.
template<int H>
__device__ __forceinline__ void stage_half(const unsigned short* __restrict__ Gb,
                                           int ld, int k0,
                                           unsigned short* matbase, int tid) {
  unsigned short* lhalf = matbase + H * 128 * 64;
#pragma unroll
  for (int i = 0; i < 2; ++i) {
    const int chunk = i * 512 + tid;     // 0..1023 within half
    const int row   = chunk >> 3;        // 0..127
    const int c16   = chunk & 7;
    const int grow  = H * 128 + row;
    gld_lds16(Gb + (size_t)grow * ld + k0 + ((c16 ^ (row & 7)) * 8),
              lhalf + chunk * 8);
  }
}

// One quadrant: A-half MH x B-half NH over K=64 -> 16 MFMA.
template<int MH, int NH>
__device__ __forceinline__ void quad(const unsigned short* __restrict__ As,
                                     const unsigned short* __restrict__ Bs,
                                     f32x4 (&acc)[8][4],
                                     int wrow, int wcol, int r, int kg) {
  bf16x8 a[4][2], b[2][2];
#pragma unroll
  for (int i = 0; i < 4; ++i) {
    const int row = MH * 128 + wrow * 64 + i * 16 + r;
#pragma unroll
    for (int kk = 0; kk < 2; ++kk) {
      const int c = kk * 4 + kg;
      a[i][kk] = *(const bf16x8*)(As + row * 64 + ((c ^ (row & 7)) * 8));
    }
  }
#pragma unroll
  for (int j = 0; j < 2; ++j) {
    const int row = NH * 128 + wcol * 32 + j * 16 + r;
#pragma unroll
    for (int kk = 0; kk < 2; ++kk) {
      const int c = kk * 4 + kg;
      b[j][kk] = *(const bf16x8*)(Bs + row * 64 + ((c ^ (row & 7)) * 8));
    }
  }
  __builtin_amdgcn_s_setprio(1);
#pragma unroll
  for (int i = 0; i < 4; ++i)
#pragma unroll
    for (int j = 0; j < 2; ++j)
#pragma unroll
      for (int kk = 0; kk < 2; ++kk)
        acc[MH * 4 + i][NH * 2 + j] = __builtin_amdgcn_mfma_f32_16x16x32_bf16(
            a[i][kk], b[j][kk], acc[MH * 4 + i][NH * 2 + j], 0, 0, 0);
  __builtin_amdgcn_s_setprio(0);
}

// C[M][N] = A[M][K] * B[N][K]^T ; A,B bf16 row-major; C fp32.
// grid: (N/256, M/256, batch), 512 threads.
__global__ __launch_bounds__(512, 2)
void gemm_bt256(const unsigned short* __restrict__ A,
                const unsigned short* __restrict__ B,
                float* __restrict__ C,
                int K, int lda, int ldb, int ldc,
                long sA, long sB, long sC) {
  __shared__ unsigned short lds[2][2][256 * 64];   // [buf][A=0/B=1] : 128 KiB

  const int tid  = threadIdx.x;
  const int lane = tid & 63;
  const int wid  = tid >> 6;
  const int wrow = wid >> 2;      // 0..1
  const int wcol = wid & 3;       // 0..3
  const int r    = lane & 15;
  const int kg   = lane >> 4;     // 0..3

  const unsigned short* Ab = A + (size_t)blockIdx.z * sA + (size_t)blockIdx.y * 256 * lda;
  const unsigned short* Bb = B + (size_t)blockIdx.z * sB + (size_t)blockIdx.x * 256 * ldb;

  f32x4 acc[8][4] = {};
  const int NT = K / 64;

  // ---- prologue: stage tile 0 into buf0, order A0,B0,A1,B1 ----
  stage_half<0>(Ab, lda, 0, &lds[0][0][0], tid);
  stage_half<0>(Bb, ldb, 0, &lds[0][1][0], tid);
  stage_half<1>(Ab, lda, 0, &lds[0][0][0], tid);
  stage_half<1>(Bb, ldb, 0, &lds[0][1][0], tid);

  // ---- main loop: tiles 0..NT-2, prefetching t+1 ----
  // per-wave VMEM queue at each tile's ph1 (oldest->newest): A0,B0,A1,B1
  for (int t = 0; t < NT - 1; ++t) {
    const unsigned short* Ac = &lds[t & 1][0][0];
    const unsigned short* Bc = &lds[t & 1][1][0];
    unsigned short* An = &lds[(t + 1) & 1][0][0];
    unsigned short* Bn = &lds[(t + 1) & 1][1][0];
    const int k1 = (t + 1) * 64;

    // phase 1: needs A0,B0 of t  -> drain to 4 (leave A1,B1 in flight)
    WAITVM(4); bar_();
    stage_half<0>(Ab, lda, k1, An, tid);   // A0' of t+1
    stage_half<0>(Bb, ldb, k1, Bn, tid);   // B0' of t+1
    quad<0, 0>(Ac, Bc, acc, wrow, wcol, r, kg);

    // phase 2: needs A1 of t -> drain to 6 (leave B1, A0', B0')
    WAITVM(6); bar_();
    stage_half<1>(Ab, lda, k1, An, tid);   // A1' of t+1
    quad<1, 0>(Ac, Bc, acc, wrow, wcol, r, kg);

    // phase 3: needs B1 of t -> drain to 6 (leave A0', B0', A1')
    WAITVM(6); bar_();
    stage_half<1>(Bb, ldb, k1, Bn, tid);   // B1' of t+1
    quad<0, 1>(Ac, Bc, acc, wrow, wcol, r, kg);

    // phase 4: everything already published
    bar_();
    quad<1, 1>(Ac, Bc, acc, wrow, wcol, r, kg);
  }

  // ---- peeled last tile: drain 4 -> 2 -> 0 ----
  {
    const unsigned short* Ac = &lds[(NT - 1) & 1][0][0];
    const unsigned short* Bc = &lds[(NT - 1) & 1][1][0];
    WAITVM(4); bar_();
    quad<0, 0>(Ac, Bc, acc, wrow, wcol, r, kg);
    WAITVM(2); bar_();
    quad<1, 0>(Ac, Bc, acc, wrow, wcol, r, kg);
    WAITVM(0); bar_();
    quad<0, 1>(Ac, Bc, acc, wrow, wcol, r, kg);
    bar_();
    quad<1, 1>(Ac, Bc, acc, wrow, wcol, r, kg);
  }

  // ---- epilogue: C/D layout col = r, row = kg*4 + j ----
  float* Cb = C + (size_t)blockIdx.z * sC;
  const int rb = blockIdx.y * 256;
  const int cb = blockIdx.x * 256;
#pragma unroll
  for (int m = 0; m < 8; ++m) {
    const int row = rb + (m >> 2) * 128 + wrow * 64 + (m & 3) * 16 + kg * 4;
#pragma unroll
    for (int n = 0; n < 4; ++n) {
      const int col = cb + (n >> 1) * 128 + wcol * 32 + (n & 1) * 16 + r;
      const f32x4 a = acc[m][n];
#pragma unroll
      for (int j = 0; j < 4; ++j)
        Cb[(size_t)(row + j) * ldc + col] = a[j];
    }
  }
}

// ---------------------------------------------------------------------------
// Kernel 2: row softmax, S (fp32, 16384 rows x 1024) -> attn (bf16).
// ---------------------------------------------------------------------------
__global__ __launch_bounds__(256) void softmax_rows(const float* __restrict__ S,
                                                    unsigned short* __restrict__ P) {
  __shared__ float redm[4];
  __shared__ float reds[4];
  const int t = threadIdx.x;
  const int wid = t >> 6, lane = t & 63;
  const size_t row = blockIdx.x;

  const float4 v = ((const float4*)(S + row * 1024))[t];

  float m = fmaxf(fmaxf(v.x, v.y), fmaxf(v.z, v.w));
#pragma unroll
  for (int o = 32; o >= 1; o >>= 1) m = fmaxf(m, __shfl_xor(m, o));
  if (lane == 0) redm[wid] = m;
  __syncthreads();
  m = fmaxf(fmaxf(redm[0], redm[1]), fmaxf(redm[2], redm[3]));

  const float e0 = expf(v.x - m), e1 = expf(v.y - m);
  const float e2 = expf(v.z - m), e3 = expf(v.w - m);
  float s = (e0 + e1) + (e2 + e3);
#pragma unroll
  for (int o = 32; o >= 1; o >>= 1) s += __shfl_xor(s, o);
  if (lane == 0) reds[wid] = s;
  __syncthreads();
  s = (reds[0] + reds[1]) + (reds[2] + reds[3]);

  const float inv = 1.0f / s;
  ushort4 u;
  u.x = f2bf(e0 * inv); u.y = f2bf(e1 * inv);
  u.z = f2bf(e2 * inv); u.w = f2bf(e3 * inv);
  ((ushort4*)(P + row * 1024))[t] = u;
}

// ---------------------------------------------------------------------------
extern "C" void kernel_launch(void* const* d_in, const int* in_sizes, int n_in,
                              void* d_out, int out_size, void* d_ws, size_t ws_size,
                              hipStream_t stream) {
  const float* x = (const float*)d_in[0];
  float* out = (float*)d_out;

  unsigned short* xb   = (unsigned short*)d_ws;
  unsigned short* xbT  = xb + (size_t)BATCH * C_DIM * N_DIM;
  unsigned short* attn = xb;          // overlays xb (dead after GEMM1)
  float* S = out;                     // scores staged in d_out, overwritten later

  cvt_xpose<<<dim3(N_DIM / 64, C_DIM / 64, BATCH), 256, 0, stream>>>(x, xb, xbT);

  // S[c][d] = sum_n xb[c][n] xb[d][n]   (M=N=1024, K=4096)
  gemm_bt256<<<dim3(C_DIM / 256, C_DIM / 256, BATCH), 512, 0, stream>>>(
      xb, xb, S, N_DIM, N_DIM, N_DIM, C_DIM,
      (long)C_DIM * N_DIM, (long)C_DIM * N_DIM, (long)C_DIM * C_DIM);

  softmax_rows<<<dim3(BATCH * C_DIM), 256, 0, stream>>>(S, attn);

  // out[c][n] = sum_d attn[c][d] xbT[n][d]  (M=1024, N=4096, K=1024)
  gemm_bt256<<<dim3(N_DIM / 256, C_DIM / 256, BATCH), 512, 0, stream>>>(
      attn, xbT, out, C_DIM, C_DIM, C_DIM, N_DIM,
      (long)C_DIM * C_DIM, (long)N_DIM * C_DIM, (long)C_DIM * N_DIM);
}